// Round 1
// baseline (266.406 us; speedup 1.0000x reference)
//
#include <hip/hip_runtime.h>

// HexaToParallelogram: out[b,s,qi,ri] = (|q+r|<=18) ? hexa[b,s,idx(q,r)] : 0
// with q=qi-18, r=ri-18, idx from the sorted (q,r) enumeration (1027 pixels).
//
// Closed-form index (verified against the Python _build_lookup construction):
//   count(q) = 37 - |q|
//   prefix(q<=0) = (55+q)(q+18)/2          (sum of counts for q' < q)
//   prefix(q>=0) = 495 + 37q - q(q-1)/2
//   r_min(q)    = max(-18, -18-q)
//   idx(q,r)    = prefix(q) + r - r_min(q)

#define IN_STRIDE   1039
#define OUT_ROW     1369        // 37*37
#define GDIM        37

__global__ __launch_bounds__(256) void HexaToParallelogram_kernel(
        const float* __restrict__ in, float* __restrict__ out, unsigned int n_elems)
{
    unsigned int t = blockIdx.x * 256u + threadIdx.x;   // one float4 per thread
    unsigned int e0 = t * 4u;
    if (e0 >= n_elems) return;

    float vals[4];
#pragma unroll
    for (int k = 0; k < 4; ++k) {
        unsigned int e = e0 + (unsigned int)k;
        // row = e / 1369, j = e % 1369  (32-bit magic-mul division by the compiler)
        unsigned int row = e / OUT_ROW;
        unsigned int j   = e - row * OUT_ROW;
        int qi = (int)(j / GDIM);
        int ri = (int)j - qi * GDIM;
        int q = qi - 18;
        int r = ri - 18;
        int s = q + r;
        float v = 0.0f;
        if (s >= -18 && s <= 18) {
            int idx;
            if (q <= 0) {
                // prefix + (r - (-18 - q))
                idx = ((55 + q) * (q + 18)) / 2 + r + 18 + q;
            } else {
                // prefix + (r + 18)
                idx = 495 + 37 * q - (q * (q - 1)) / 2 + r + 18;
            }
            v = in[(size_t)row * IN_STRIDE + (size_t)idx];
        }
        vals[k] = v;
    }

    if (e0 + 3u < n_elems) {
        float4 o;
        o.x = vals[0]; o.y = vals[1]; o.z = vals[2]; o.w = vals[3];
        reinterpret_cast<float4*>(out)[t] = o;
    } else {
        // tail (never hit for 44,859,392 but keep it correct in general)
        for (unsigned int k = 0; k < 4 && e0 + k < n_elems; ++k)
            out[e0 + k] = vals[k];
    }
}

extern "C" void kernel_launch(void* const* d_in, const int* in_sizes, int n_in,
                              void* d_out, int out_size, void* d_ws, size_t ws_size,
                              hipStream_t stream)
{
    const float* in = (const float*)d_in[0];
    float* out = (float*)d_out;
    unsigned int n = (unsigned int)out_size;          // 64*512*37*37 = 44,859,392
    unsigned int n4 = (n + 3u) / 4u;                  // float4s
    unsigned int blocks = (n4 + 255u) / 256u;         // 43,808
    HexaToParallelogram_kernel<<<blocks, 256, 0, stream>>>(in, out, n);
}